// Round 16
// baseline (153.654 us; speedup 1.0000x reference)
//
#include <hip/hip_runtime.h>
#include <hip/hip_bf16.h>
#include <hip/hip_fp16.h>

#define N_NODES 40000
#define N_EDGES 640000
#define DIM 128
#define N_OPS 5
#define EPS 1e-5f
#define CAP 64                        // fixed CSR stride; P(deg>=64) ~ 1e-19/node
#define GATHER_NB 2048
#define STAT_NB 512
#define FCB 3072                      // fused fill/conv blocks: 2560 fill + 512 stats
#define SW (N_OPS * DIM)              // 640; ssum_ssq = [sums(640) | ssqs(640)]
#define NZERO (N_NODES + 2 * SW)      // 41280 ints, cnt..ssum_ssq contiguous

// ---- K0: custom zero of cnt + ssum_ssq ----
__global__ void __launch_bounds__(256)
zero_kernel(int4* __restrict__ p) {
  const int i = blockIdx.x * blockDim.x + threadIdx.x;
  if (i < NZERO / 4) p[i] = make_int4(0, 0, 0, 0);
}

// ---- K1: role-split fused kernel.
//      blocks with b%6==5 (512, interleaved -> co-resident): h->fp16 conv + stats01.
//      other 2560 blocks: 1-edge/thread CSR fill (atomic-latency-bound).
//      The BW-bound stream and latency-bound scatter co-run on the CUs. ----
__global__ void __launch_bounds__(256)
fill_conv_kernel(const int* __restrict__ ei, int* __restrict__ cnt,
                 unsigned short* __restrict__ csr_src,
                 const float* __restrict__ h, const float* __restrict__ h_in,
                 __half* __restrict__ h16, float* __restrict__ ssum_ssq) {
  const int b   = blockIdx.x;
  const int tid = threadIdx.x;
  const bool is_stats = (b % 6) == 5;

  if (!is_stats) {
    // ---- fill role: compact index over non-stats blocks ----
    const int fill_idx = b - b / 6;          // 0..2559
    const int e = fill_idx * 256 + tid;      // 2560*256 = 655360 >= N_EDGES
    if (e < N_EDGES) {
      const int s = ei[e];
      const int d = ei[N_EDGES + e];
      const int p = atomicAdd(&cnt[d], 1);
      if (p < CAP) csr_src[d * CAP + p] = (unsigned short)s;
    }
    return;
  }

  // ---- stats role ----
  __shared__ float lsum[2 * DIM], lssq[2 * DIM];
  for (int i = tid; i < 2 * DIM; i += 256) { lsum[i] = 0.f; lssq[i] = 0.f; }
  __syncthreads();

  const int sidx = b / 6;                    // 0..511
  const int gtid = sidx * 256 + tid;
  const int gsz  = STAT_NB * 256;            // mult of 32 -> column fixed
  float s0[4] = {0, 0, 0, 0}, q0[4] = {0, 0, 0, 0};
  float s1[4] = {0, 0, 0, 0}, q1[4] = {0, 0, 0, 0};
  const int NG = N_NODES * (DIM / 4);
  for (int g = gtid; g < NG; g += gsz) {
    const float4 a = reinterpret_cast<const float4*>(h)[g];
    const float4 b4 = reinterpret_cast<const float4*>(h_in)[g];
    const __half2 lo = __float22half2_rn(make_float2(a.x, a.y));
    const __half2 hi = __float22half2_rn(make_float2(a.z, a.w));
    uint2 pk;
    pk.x = *reinterpret_cast<const unsigned*>(&lo);
    pk.y = *reinterpret_cast<const unsigned*>(&hi);
    reinterpret_cast<uint2*>(h16)[g] = pk;
    s0[0] += a.x;  q0[0] += a.x * a.x;   s0[1] += a.y;  q0[1] += a.y * a.y;
    s0[2] += a.z;  q0[2] += a.z * a.z;   s0[3] += a.w;  q0[3] += a.w * a.w;
    s1[0] += b4.x; q1[0] += b4.x * b4.x; s1[1] += b4.y; q1[1] += b4.y * b4.y;
    s1[2] += b4.z; q1[2] += b4.z * b4.z; s1[3] += b4.w; q1[3] += b4.w * b4.w;
  }
  const int c4 = (tid & 31) * 4;
#pragma unroll
  for (int j = 0; j < 4; ++j) {
    atomicAdd(&lsum[0 * DIM + c4 + j], s0[j]);
    atomicAdd(&lsum[1 * DIM + c4 + j], s1[j]);
    atomicAdd(&lssq[0 * DIM + c4 + j], q0[j]);
    atomicAdd(&lssq[1 * DIM + c4 + j], q1[j]);
  }
  __syncthreads();
  for (int i = tid; i < 2 * DIM; i += 256) {
    unsafeAtomicAdd(&ssum_ssq[i], lsum[i]);
    unsafeAtomicAdd(&ssum_ssq[SW + i], lssq[i]);
  }
}

// ---- K2: fp16 gather — 4 edges per wave-instruction (quarter-wave, 16B/lane) ----
__global__ void __launch_bounds__(256)
gather_kernel(const unsigned short* __restrict__ csr_src,
              const int* __restrict__ cnt,
              const __half* __restrict__ h16,
              float* __restrict__ agg_sum,
              float* __restrict__ agg_max) {
  const int lane = threadIdx.x & 63;
  const int q    = lane >> 4;               // quarter 0..3 -> edge slot
  const int cl   = lane & 15;               // 16 lanes cover the row: 8 cols each
  const int wave  = (int)((blockIdx.x * blockDim.x + threadIdx.x) >> 6);
  const int nwave = (int)((gridDim.x * blockDim.x) >> 6);

  for (int n = wave; n < N_NODES; n += nwave) {
    const int dgf = cnt[n];
    const int dg  = (dgf < CAP) ? dgf : CAP;
    const int beg = n * CAP, end = beg + dg;
    float s0 = 0.f, s1 = 0.f, s2 = 0.f, s3 = 0.f;
    float s4 = 0.f, s5 = 0.f, s6 = 0.f, s7 = 0.f;
    float m0 = -INFINITY, m1 = -INFINITY, m2 = -INFINITY, m3 = -INFINITY;
    float m4 = -INFINITY, m5 = -INFINITY, m6 = -INFINITY, m7 = -INFINITY;
    for (int e = beg; e < end; e += 4) {
      const int idx = e + q;
      if (idx < end) {
        const int s = (int)csr_src[idx];
        const uint4 rv = reinterpret_cast<const uint4*>(h16)[s * (DIM / 8) + cl];
        const float2 f0 = __half22float2(*reinterpret_cast<const __half2*>(&rv.x));
        const float2 f1 = __half22float2(*reinterpret_cast<const __half2*>(&rv.y));
        const float2 f2 = __half22float2(*reinterpret_cast<const __half2*>(&rv.z));
        const float2 f3 = __half22float2(*reinterpret_cast<const __half2*>(&rv.w));
        s0 += f0.x; s1 += f0.y; s2 += f1.x; s3 += f1.y;
        s4 += f2.x; s5 += f2.y; s6 += f3.x; s7 += f3.y;
        m0 = fmaxf(m0, f0.x); m1 = fmaxf(m1, f0.y);
        m2 = fmaxf(m2, f1.x); m3 = fmaxf(m3, f1.y);
        m4 = fmaxf(m4, f2.x); m5 = fmaxf(m5, f2.y);
        m6 = fmaxf(m6, f3.x); m7 = fmaxf(m7, f3.y);
      }
    }
    // combine the 4 quarters: butterfly over lane bits 4,5
#pragma unroll
    for (int off = 16; off < 64; off <<= 1) {
      s0 += __shfl_xor(s0, off, 64); s1 += __shfl_xor(s1, off, 64);
      s2 += __shfl_xor(s2, off, 64); s3 += __shfl_xor(s3, off, 64);
      s4 += __shfl_xor(s4, off, 64); s5 += __shfl_xor(s5, off, 64);
      s6 += __shfl_xor(s6, off, 64); s7 += __shfl_xor(s7, off, 64);
      m0 = fmaxf(m0, __shfl_xor(m0, off, 64)); m1 = fmaxf(m1, __shfl_xor(m1, off, 64));
      m2 = fmaxf(m2, __shfl_xor(m2, off, 64)); m3 = fmaxf(m3, __shfl_xor(m3, off, 64));
      m4 = fmaxf(m4, __shfl_xor(m4, off, 64)); m5 = fmaxf(m5, __shfl_xor(m5, off, 64));
      m6 = fmaxf(m6, __shfl_xor(m6, off, 64)); m7 = fmaxf(m7, __shfl_xor(m7, off, 64));
    }
    if (dgf == 0) {
      m0 = 0.f; m1 = 0.f; m2 = 0.f; m3 = 0.f;
      m4 = 0.f; m5 = 0.f; m6 = 0.f; m7 = 0.f;   // empty segment -> 0 (isfinite mask)
    }
    const size_t off8 = (size_t)n * DIM + cl * 8;
    if (q == 0) {
      *reinterpret_cast<float4*>(agg_sum + off8)     = make_float4(s0, s1, s2, s3);
      *reinterpret_cast<float4*>(agg_sum + off8 + 4) = make_float4(s4, s5, s6, s7);
    } else if (q == 1) {
      *reinterpret_cast<float4*>(agg_max + off8)     = make_float4(m0, m1, m2, m3);
      *reinterpret_cast<float4*>(agg_max + off8 + 4) = make_float4(m4, m5, m6, m7);
    }
  }
}

// ---- K3: branch-2/3/4 column stats from agg_sum/agg_max (L2/L3-hot) ----
__global__ void __launch_bounds__(256)
stats234_kernel(const float* __restrict__ agg_sum,
                const float* __restrict__ agg_max,
                const int* __restrict__ cnt,
                float* __restrict__ ssum_ssq) {
  __shared__ float lsum[3 * DIM], lssq[3 * DIM];
  for (int i = threadIdx.x; i < 3 * DIM; i += 256) { lsum[i] = 0.f; lssq[i] = 0.f; }
  __syncthreads();

  const int gtid = blockIdx.x * 256 + threadIdx.x;
  const int gsz  = gridDim.x * 256;           // 512*256 (mult of 32)
  float s2[4] = {0, 0, 0, 0}, q2[4] = {0, 0, 0, 0};
  float s3[4] = {0, 0, 0, 0}, q3[4] = {0, 0, 0, 0};
  float s4[4] = {0, 0, 0, 0}, q4[4] = {0, 0, 0, 0};
  const int NG = N_NODES * (DIM / 4);
  for (int g = gtid; g < NG; g += gsz) {
    const int n = g >> 5;
    const float4 v2 = reinterpret_cast<const float4*>(agg_sum)[g];
    const float4 v4 = reinterpret_cast<const float4*>(agg_max)[g];
    const float inv = 1.0f / fmaxf((float)cnt[n], 1.0f);
    const float a0 = v2.x * inv, a1 = v2.y * inv, a2 = v2.z * inv, a3 = v2.w * inv;
    s2[0] += v2.x; q2[0] += v2.x * v2.x;  s2[1] += v2.y; q2[1] += v2.y * v2.y;
    s2[2] += v2.z; q2[2] += v2.z * v2.z;  s2[3] += v2.w; q2[3] += v2.w * v2.w;
    s3[0] += a0;   q3[0] += a0 * a0;      s3[1] += a1;   q3[1] += a1 * a1;
    s3[2] += a2;   q3[2] += a2 * a2;      s3[3] += a3;   q3[3] += a3 * a3;
    s4[0] += v4.x; q4[0] += v4.x * v4.x;  s4[1] += v4.y; q4[1] += v4.y * v4.y;
    s4[2] += v4.z; q4[2] += v4.z * v4.z;  s4[3] += v4.w; q4[3] += v4.w * v4.w;
  }
  const int c4 = (threadIdx.x & 31) * 4;
#pragma unroll
  for (int j = 0; j < 4; ++j) {
    atomicAdd(&lsum[0 * DIM + c4 + j], s2[j]);
    atomicAdd(&lsum[1 * DIM + c4 + j], s3[j]);
    atomicAdd(&lsum[2 * DIM + c4 + j], s4[j]);
    atomicAdd(&lssq[0 * DIM + c4 + j], q2[j]);
    atomicAdd(&lssq[1 * DIM + c4 + j], q3[j]);
    atomicAdd(&lssq[2 * DIM + c4 + j], q4[j]);
  }
  __syncthreads();
  for (int i = threadIdx.x; i < 3 * DIM; i += 256) {
    unsafeAtomicAdd(&ssum_ssq[2 * DIM + i], lsum[i]);
    unsafeAtomicAdd(&ssum_ssq[SW + 2 * DIM + i], lssq[i]);
  }
}

// ---- K4: fused BN + ReLU + weighted sum (derives mu/rsig in-block) ----
__global__ void out_kernel(const float* __restrict__ h,
                           const float* __restrict__ h_in,
                           const float* __restrict__ agg_sum,
                           const float* __restrict__ agg_max,
                           const int* __restrict__ cnt,
                           const float* __restrict__ ssum_ssq,
                           const float* __restrict__ gamma,
                           const float* __restrict__ beta,
                           const float* __restrict__ w,
                           float* __restrict__ out) {
  __shared__ float smu[SW], srs[SW], sg[SW], sb[SW];
  __shared__ float sw[N_OPS];
  const float invn = 1.0f / (float)N_NODES;
  for (int i = threadIdx.x; i < SW; i += blockDim.x) {
    const float m = ssum_ssq[i] * invn;
    float v = ssum_ssq[SW + i] * invn - m * m;
    v = fmaxf(v, 0.0f);
    smu[i] = m;
    srs[i] = rsqrtf(v + EPS);
    sg[i] = gamma[i]; sb[i] = beta[i];
  }
  if (threadIdx.x < N_OPS) sw[threadIdx.x] = w[threadIdx.x];
  __syncthreads();

  const int ngroups = N_NODES * (DIM / 4);
  for (int g = blockIdx.x * blockDim.x + threadIdx.x; g < ngroups;
       g += gridDim.x * blockDim.x) {
    const int n  = g >> 5;
    const int d4 = (g & 31) * 4;
    const size_t off = (size_t)n * DIM + d4;

    const float4 v0 = *reinterpret_cast<const float4*>(h + off);
    const float4 v1 = *reinterpret_cast<const float4*>(h_in + off);
    const float4 v2 = *reinterpret_cast<const float4*>(agg_sum + off);
    const float4 v4 = *reinterpret_cast<const float4*>(agg_max + off);
    const float inv = 1.0f / fmaxf((float)cnt[n], 1.0f);

    float vals[N_OPS][4];
    vals[0][0] = v0.x; vals[0][1] = v0.y; vals[0][2] = v0.z; vals[0][3] = v0.w;
    vals[1][0] = v1.x; vals[1][1] = v1.y; vals[1][2] = v1.z; vals[1][3] = v1.w;
    vals[2][0] = v2.x; vals[2][1] = v2.y; vals[2][2] = v2.z; vals[2][3] = v2.w;
    vals[3][0] = v2.x * inv; vals[3][1] = v2.y * inv;
    vals[3][2] = v2.z * inv; vals[3][3] = v2.w * inv;
    vals[4][0] = v4.x; vals[4][1] = v4.y; vals[4][2] = v4.z; vals[4][3] = v4.w;

    float acc[4] = {0.0f, 0.0f, 0.0f, 0.0f};
#pragma unroll
    for (int b = 0; b < N_OPS; ++b) {
      const float wb = sw[b];
#pragma unroll
      for (int c = 0; c < 4; ++c) {
        const int dd = b * DIM + d4 + c;
        const float xh = (vals[b][c] - smu[dd]) * srs[dd];
        const float y  = fmaf(sg[dd], xh, sb[dd]);
        acc[c] = fmaf(wb, fmaxf(y, 0.0f), acc[c]);
      }
    }
    *reinterpret_cast<float4*>(out + off) = make_float4(acc[0], acc[1], acc[2], acc[3]);
  }
}

extern "C" void kernel_launch(void* const* d_in, const int* in_sizes, int n_in,
                              void* d_out, int out_size, void* d_ws, size_t ws_size,
                              hipStream_t stream) {
  const float* w     = (const float*)d_in[0];
  const int*   ei    = (const int*)d_in[1];
  const float* h     = (const float*)d_in[2];
  const float* h_in  = (const float*)d_in[3];
  const float* gamma = (const float*)d_in[4];
  const float* beta  = (const float*)d_in[5];
  float* out = (float*)d_out;

  const size_t ND = (size_t)N_NODES * DIM;
  float*  ws       = (float*)d_ws;
  float*  agg_sum  = ws;                                 // ND floats
  int*    cnt      = (int*)(ws + ND);                    // N ints      <- zeroed
  float*  ssum_ssq = (float*)(cnt + N_NODES);            // 1280 floats <- zeroed (contig)
  unsigned short* csr_src = (unsigned short*)(ssum_ssq + 2 * SW); // N*CAP u16 (5.12 MB)
  __half* h16      = (__half*)(csr_src + N_NODES * CAP); // ND halves (10.24 MB, 16B-aligned)
  float*  agg_max  = out;                                // ND floats (overwritten last)

  zero_kernel<<<(NZERO / 4 + 255) / 256, 256, 0, stream>>>((int4*)cnt);
  fill_conv_kernel<<<FCB, 256, 0, stream>>>(ei, cnt, csr_src, h, h_in, h16, ssum_ssq);
  gather_kernel<<<GATHER_NB, 256, 0, stream>>>(csr_src, cnt, h16, agg_sum, agg_max);
  stats234_kernel<<<STAT_NB, 256, 0, stream>>>(agg_sum, agg_max, cnt, ssum_ssq);
  out_kernel<<<2048, 256, 0, stream>>>(h, h_in, agg_sum, agg_max, cnt, ssum_ssq,
                                       gamma, beta, w, out);
}

// Round 17
// 143.007 us; speedup vs baseline: 1.0745x; 1.0745x over previous
//
#include <hip/hip_runtime.h>
#include <hip/hip_bf16.h>
#include <hip/hip_fp16.h>

#define N_NODES 40000
#define N_EDGES 640000
#define DIM 128
#define N_OPS 5
#define EPS 1e-5f
#define CAP 64                        // fixed CSR stride; P(deg>=64) ~ 1e-19/node
#define GATHER_NB 2048
#define STAT_NB 512
#define SW (N_OPS * DIM)              // 640; ssum_ssq = [sums(640) | ssqs(640)]
#define NZERO (N_NODES + 2 * SW)      // 41280 ints, cnt..ssum_ssq contiguous

__device__ __forceinline__ unsigned pack2(float a, float b) {
  const __half2 t = __float22half2_rn(make_float2(a, b));
  return *reinterpret_cast<const unsigned*>(&t);
}
__device__ __forceinline__ float2 unpack2(unsigned u) {
  return __half22float2(*reinterpret_cast<const __half2*>(&u));
}

// ---- K0: custom zero of cnt + ssum_ssq ----
__global__ void __launch_bounds__(256)
zero_kernel(int4* __restrict__ p) {
  const int i = blockIdx.x * blockDim.x + threadIdx.x;
  if (i < NZERO / 4) p[i] = make_int4(0, 0, 0, 0);
}

// ---- K1: fixed-stride CSR fill, 1 edge/thread (R12-proven), ushort ids ----
__global__ void __launch_bounds__(256)
fill_kernel(const int* __restrict__ ei, int* __restrict__ cnt,
            unsigned short* __restrict__ csr_src) {
  const int e = blockIdx.x * blockDim.x + threadIdx.x;
  if (e < N_EDGES) {
    const int s = ei[e];
    const int d = ei[N_EDGES + e];
    const int p = atomicAdd(&cnt[d], 1);
    if (p < CAP) csr_src[d * CAP + p] = (unsigned short)s;
  }
}

// ---- K2: h -> fp16 conversion + branch-0/1 column stats (BW-bound stream) ----
__global__ void __launch_bounds__(256)
conv_stats01_kernel(const float* __restrict__ h, const float* __restrict__ h_in,
                    __half* __restrict__ h16, float* __restrict__ ssum_ssq) {
  __shared__ float lsum[2 * DIM], lssq[2 * DIM];
  for (int i = threadIdx.x; i < 2 * DIM; i += 256) { lsum[i] = 0.f; lssq[i] = 0.f; }
  __syncthreads();

  const int gtid = blockIdx.x * 256 + threadIdx.x;
  const int gsz  = STAT_NB * 256;            // mult of 32 -> column fixed
  float s0[4] = {0, 0, 0, 0}, q0[4] = {0, 0, 0, 0};
  float s1[4] = {0, 0, 0, 0}, q1[4] = {0, 0, 0, 0};
  const int NG = N_NODES * (DIM / 4);
  for (int g = gtid; g < NG; g += gsz) {
    const float4 a = reinterpret_cast<const float4*>(h)[g];
    const float4 b = reinterpret_cast<const float4*>(h_in)[g];
    uint2 pk;
    pk.x = pack2(a.x, a.y);
    pk.y = pack2(a.z, a.w);
    reinterpret_cast<uint2*>(h16)[g] = pk;
    s0[0] += a.x; q0[0] += a.x * a.x;  s0[1] += a.y; q0[1] += a.y * a.y;
    s0[2] += a.z; q0[2] += a.z * a.z;  s0[3] += a.w; q0[3] += a.w * a.w;
    s1[0] += b.x; q1[0] += b.x * b.x;  s1[1] += b.y; q1[1] += b.y * b.y;
    s1[2] += b.z; q1[2] += b.z * b.z;  s1[3] += b.w; q1[3] += b.w * b.w;
  }
  const int c4 = (threadIdx.x & 31) * 4;
#pragma unroll
  for (int j = 0; j < 4; ++j) {
    atomicAdd(&lsum[0 * DIM + c4 + j], s0[j]);
    atomicAdd(&lsum[1 * DIM + c4 + j], s1[j]);
    atomicAdd(&lssq[0 * DIM + c4 + j], q0[j]);
    atomicAdd(&lssq[1 * DIM + c4 + j], q1[j]);
  }
  __syncthreads();
  for (int i = threadIdx.x; i < 2 * DIM; i += 256) {
    unsafeAtomicAdd(&ssum_ssq[i], lsum[i]);
    unsafeAtomicAdd(&ssum_ssq[SW + i], lssq[i]);
  }
}

// ---- K3: fp16 gather — 4 edges per wave-instruction; fp16 agg outputs ----
__global__ void __launch_bounds__(256)
gather_kernel(const unsigned short* __restrict__ csr_src,
              const int* __restrict__ cnt,
              const __half* __restrict__ h16,
              __half* __restrict__ agg_sum16,
              __half* __restrict__ agg_max16) {
  const int lane = threadIdx.x & 63;
  const int q    = lane >> 4;               // quarter 0..3 -> edge slot
  const int cl   = lane & 15;               // 16 lanes cover the row: 8 cols each
  const int wave  = (int)((blockIdx.x * blockDim.x + threadIdx.x) >> 6);
  const int nwave = (int)((gridDim.x * blockDim.x) >> 6);

  for (int n = wave; n < N_NODES; n += nwave) {
    const int dgf = cnt[n];
    const int dg  = (dgf < CAP) ? dgf : CAP;
    const int beg = n * CAP, end = beg + dg;
    float s0 = 0.f, s1 = 0.f, s2 = 0.f, s3 = 0.f;
    float s4 = 0.f, s5 = 0.f, s6 = 0.f, s7 = 0.f;
    float m0 = -INFINITY, m1 = -INFINITY, m2 = -INFINITY, m3 = -INFINITY;
    float m4 = -INFINITY, m5 = -INFINITY, m6 = -INFINITY, m7 = -INFINITY;
    for (int e = beg; e < end; e += 4) {
      const int idx = e + q;
      if (idx < end) {
        const int s = (int)csr_src[idx];
        const uint4 rv = reinterpret_cast<const uint4*>(h16)[s * (DIM / 8) + cl];
        const float2 f0 = unpack2(rv.x);
        const float2 f1 = unpack2(rv.y);
        const float2 f2 = unpack2(rv.z);
        const float2 f3 = unpack2(rv.w);
        s0 += f0.x; s1 += f0.y; s2 += f1.x; s3 += f1.y;
        s4 += f2.x; s5 += f2.y; s6 += f3.x; s7 += f3.y;
        m0 = fmaxf(m0, f0.x); m1 = fmaxf(m1, f0.y);
        m2 = fmaxf(m2, f1.x); m3 = fmaxf(m3, f1.y);
        m4 = fmaxf(m4, f2.x); m5 = fmaxf(m5, f2.y);
        m6 = fmaxf(m6, f3.x); m7 = fmaxf(m7, f3.y);
      }
    }
    // combine the 4 quarters: butterfly over lane bits 4,5
#pragma unroll
    for (int off = 16; off < 64; off <<= 1) {
      s0 += __shfl_xor(s0, off, 64); s1 += __shfl_xor(s1, off, 64);
      s2 += __shfl_xor(s2, off, 64); s3 += __shfl_xor(s3, off, 64);
      s4 += __shfl_xor(s4, off, 64); s5 += __shfl_xor(s5, off, 64);
      s6 += __shfl_xor(s6, off, 64); s7 += __shfl_xor(s7, off, 64);
      m0 = fmaxf(m0, __shfl_xor(m0, off, 64)); m1 = fmaxf(m1, __shfl_xor(m1, off, 64));
      m2 = fmaxf(m2, __shfl_xor(m2, off, 64)); m3 = fmaxf(m3, __shfl_xor(m3, off, 64));
      m4 = fmaxf(m4, __shfl_xor(m4, off, 64)); m5 = fmaxf(m5, __shfl_xor(m5, off, 64));
      m6 = fmaxf(m6, __shfl_xor(m6, off, 64)); m7 = fmaxf(m7, __shfl_xor(m7, off, 64));
    }
    if (dgf == 0) {
      m0 = 0.f; m1 = 0.f; m2 = 0.f; m3 = 0.f;
      m4 = 0.f; m5 = 0.f; m6 = 0.f; m7 = 0.f;   // empty segment -> 0 (isfinite mask)
    }
    const int g8 = n * (DIM / 8) + cl;           // uint4 index of my 8 halves
    if (q == 0) {
      uint4 pk;
      pk.x = pack2(s0, s1); pk.y = pack2(s2, s3);
      pk.z = pack2(s4, s5); pk.w = pack2(s6, s7);
      reinterpret_cast<uint4*>(agg_sum16)[g8] = pk;
    } else if (q == 1) {
      uint4 pk;
      pk.x = pack2(m0, m1); pk.y = pack2(m2, m3);
      pk.z = pack2(m4, m5); pk.w = pack2(m6, m7);
      reinterpret_cast<uint4*>(agg_max16)[g8] = pk;
    }
  }
}

// ---- K4: branch-2/3/4 column stats from fp16 agg (L2/L3-hot) ----
__global__ void __launch_bounds__(256)
stats234_kernel(const __half* __restrict__ agg_sum16,
                const __half* __restrict__ agg_max16,
                const int* __restrict__ cnt,
                float* __restrict__ ssum_ssq) {
  __shared__ float lsum[3 * DIM], lssq[3 * DIM];
  for (int i = threadIdx.x; i < 3 * DIM; i += 256) { lsum[i] = 0.f; lssq[i] = 0.f; }
  __syncthreads();

  const int gtid = blockIdx.x * 256 + threadIdx.x;
  const int gsz  = gridDim.x * 256;           // 512*256 (mult of 32)
  float s2[4] = {0, 0, 0, 0}, q2[4] = {0, 0, 0, 0};
  float s3[4] = {0, 0, 0, 0}, q3[4] = {0, 0, 0, 0};
  float s4[4] = {0, 0, 0, 0}, q4[4] = {0, 0, 0, 0};
  const int NG = N_NODES * (DIM / 4);
  for (int g = gtid; g < NG; g += gsz) {
    const int n = g >> 5;
    const uint2 u2 = reinterpret_cast<const uint2*>(agg_sum16)[g];
    const uint2 u4 = reinterpret_cast<const uint2*>(agg_max16)[g];
    const float2 v2lo = unpack2(u2.x), v2hi = unpack2(u2.y);
    const float2 v4lo = unpack2(u4.x), v4hi = unpack2(u4.y);
    const float inv = 1.0f / fmaxf((float)cnt[n], 1.0f);
    const float a0 = v2lo.x * inv, a1 = v2lo.y * inv;
    const float a2 = v2hi.x * inv, a3 = v2hi.y * inv;
    s2[0] += v2lo.x; q2[0] += v2lo.x * v2lo.x;  s2[1] += v2lo.y; q2[1] += v2lo.y * v2lo.y;
    s2[2] += v2hi.x; q2[2] += v2hi.x * v2hi.x;  s2[3] += v2hi.y; q2[3] += v2hi.y * v2hi.y;
    s3[0] += a0;     q3[0] += a0 * a0;          s3[1] += a1;     q3[1] += a1 * a1;
    s3[2] += a2;     q3[2] += a2 * a2;          s3[3] += a3;     q3[3] += a3 * a3;
    s4[0] += v4lo.x; q4[0] += v4lo.x * v4lo.x;  s4[1] += v4lo.y; q4[1] += v4lo.y * v4lo.y;
    s4[2] += v4hi.x; q4[2] += v4hi.x * v4hi.x;  s4[3] += v4hi.y; q4[3] += v4hi.y * v4hi.y;
  }
  const int c4 = (threadIdx.x & 31) * 4;
#pragma unroll
  for (int j = 0; j < 4; ++j) {
    atomicAdd(&lsum[0 * DIM + c4 + j], s2[j]);
    atomicAdd(&lsum[1 * DIM + c4 + j], s3[j]);
    atomicAdd(&lsum[2 * DIM + c4 + j], s4[j]);
    atomicAdd(&lssq[0 * DIM + c4 + j], q2[j]);
    atomicAdd(&lssq[1 * DIM + c4 + j], q3[j]);
    atomicAdd(&lssq[2 * DIM + c4 + j], q4[j]);
  }
  __syncthreads();
  for (int i = threadIdx.x; i < 3 * DIM; i += 256) {
    unsafeAtomicAdd(&ssum_ssq[2 * DIM + i], lsum[i]);
    unsafeAtomicAdd(&ssum_ssq[SW + 2 * DIM + i], lssq[i]);
  }
}

// ---- K5: fused BN + ReLU + weighted sum (derives mu/rsig in-block) ----
__global__ void out_kernel(const float* __restrict__ h,
                           const float* __restrict__ h_in,
                           const __half* __restrict__ agg_sum16,
                           const __half* __restrict__ agg_max16,
                           const int* __restrict__ cnt,
                           const float* __restrict__ ssum_ssq,
                           const float* __restrict__ gamma,
                           const float* __restrict__ beta,
                           const float* __restrict__ w,
                           float* __restrict__ out) {
  __shared__ float smu[SW], srs[SW], sg[SW], sb[SW];
  __shared__ float sw[N_OPS];
  const float invn = 1.0f / (float)N_NODES;
  for (int i = threadIdx.x; i < SW; i += blockDim.x) {
    const float m = ssum_ssq[i] * invn;
    float v = ssum_ssq[SW + i] * invn - m * m;
    v = fmaxf(v, 0.0f);
    smu[i] = m;
    srs[i] = rsqrtf(v + EPS);
    sg[i] = gamma[i]; sb[i] = beta[i];
  }
  if (threadIdx.x < N_OPS) sw[threadIdx.x] = w[threadIdx.x];
  __syncthreads();

  const int ngroups = N_NODES * (DIM / 4);
  for (int g = blockIdx.x * blockDim.x + threadIdx.x; g < ngroups;
       g += gridDim.x * blockDim.x) {
    const int n  = g >> 5;
    const int d4 = (g & 31) * 4;
    const size_t off = (size_t)n * DIM + d4;

    const float4 v0 = *reinterpret_cast<const float4*>(h + off);
    const float4 v1 = *reinterpret_cast<const float4*>(h_in + off);
    const uint2 u2 = reinterpret_cast<const uint2*>(agg_sum16)[g];
    const uint2 u4 = reinterpret_cast<const uint2*>(agg_max16)[g];
    const float2 v2lo = unpack2(u2.x), v2hi = unpack2(u2.y);
    const float2 v4lo = unpack2(u4.x), v4hi = unpack2(u4.y);
    const float inv = 1.0f / fmaxf((float)cnt[n], 1.0f);

    float vals[N_OPS][4];
    vals[0][0] = v0.x;   vals[0][1] = v0.y;   vals[0][2] = v0.z;   vals[0][3] = v0.w;
    vals[1][0] = v1.x;   vals[1][1] = v1.y;   vals[1][2] = v1.z;   vals[1][3] = v1.w;
    vals[2][0] = v2lo.x; vals[2][1] = v2lo.y; vals[2][2] = v2hi.x; vals[2][3] = v2hi.y;
    vals[3][0] = v2lo.x * inv; vals[3][1] = v2lo.y * inv;
    vals[3][2] = v2hi.x * inv; vals[3][3] = v2hi.y * inv;
    vals[4][0] = v4lo.x; vals[4][1] = v4lo.y; vals[4][2] = v4hi.x; vals[4][3] = v4hi.y;

    float acc[4] = {0.0f, 0.0f, 0.0f, 0.0f};
#pragma unroll
    for (int b = 0; b < N_OPS; ++b) {
      const float wb = sw[b];
#pragma unroll
      for (int c = 0; c < 4; ++c) {
        const int dd = b * DIM + d4 + c;
        const float xh = (vals[b][c] - smu[dd]) * srs[dd];
        const float y  = fmaf(sg[dd], xh, sb[dd]);
        acc[c] = fmaf(wb, fmaxf(y, 0.0f), acc[c]);
      }
    }
    *reinterpret_cast<float4*>(out + off) = make_float4(acc[0], acc[1], acc[2], acc[3]);
  }
}

extern "C" void kernel_launch(void* const* d_in, const int* in_sizes, int n_in,
                              void* d_out, int out_size, void* d_ws, size_t ws_size,
                              hipStream_t stream) {
  const float* w     = (const float*)d_in[0];
  const int*   ei    = (const int*)d_in[1];
  const float* h     = (const float*)d_in[2];
  const float* h_in  = (const float*)d_in[3];
  const float* gamma = (const float*)d_in[4];
  const float* beta  = (const float*)d_in[5];
  float* out = (float*)d_out;

  const size_t ND = (size_t)N_NODES * DIM;
  int*    cnt      = (int*)d_ws;                         // N ints      <- zeroed
  float*  ssum_ssq = (float*)(cnt + N_NODES);            // 1280 floats <- zeroed (contig)
  unsigned short* csr_src = (unsigned short*)(ssum_ssq + 2 * SW); // N*CAP u16 (5.12 MB)
  __half* h16      = (__half*)(csr_src + N_NODES * CAP); // ND halves (10.24 MB)
  __half* agg_sum16 = h16 + ND;                          // ND halves (10.24 MB)
  __half* agg_max16 = agg_sum16 + ND;                    // ND halves (10.24 MB)

  zero_kernel<<<(NZERO / 4 + 255) / 256, 256, 0, stream>>>((int4*)cnt);
  fill_kernel<<<(N_EDGES + 255) / 256, 256, 0, stream>>>(ei, cnt, csr_src);
  conv_stats01_kernel<<<STAT_NB, 256, 0, stream>>>(h, h_in, h16, ssum_ssq);
  gather_kernel<<<GATHER_NB, 256, 0, stream>>>(csr_src, cnt, h16, agg_sum16, agg_max16);
  stats234_kernel<<<STAT_NB, 256, 0, stream>>>(agg_sum16, agg_max16, cnt, ssum_ssq);
  out_kernel<<<2048, 256, 0, stream>>>(h, h_in, agg_sum16, agg_max16, cnt, ssum_ssq,
                                       gamma, beta, w, out);
}